// Round 1
// baseline (473.104 us; speedup 1.0000x reference)
//
#include <hip/hip_runtime.h>
#include <hip/hip_bf16.h>

#define H_DIM 2048
#define B_SZ  8
#define SEQ   1024
#define M_DIM (B_SZ*SEQ)   // 8192

using f32x4 = __attribute__((ext_vector_type(4))) float;
using s16x8 = __attribute__((ext_vector_type(8))) short;

__device__ __forceinline__ float bf2f(unsigned short u) {
  unsigned int x = ((unsigned int)u) << 16;
  return __builtin_bit_cast(float, x);
}
__device__ __forceinline__ unsigned short f2bf(float f) {
  unsigned int x = __builtin_bit_cast(unsigned int, f);
  unsigned int r = (x + 0x7fffu + ((x >> 16) & 1u)) >> 16;
  return (unsigned short)r;
}

__device__ __forceinline__ void gl_lds16(const void* g, void* l) {
  __builtin_amdgcn_global_load_lds(
      (__attribute__((address_space(1))) void*)g,
      (__attribute__((address_space(3))) void*)l, 16, 0, 0);
}

// ---------------- transpose fp32 [R][C] -> bf16 [C][R] ----------------
__global__ __launch_bounds__(256) void transpose_kernel(
    const float* __restrict__ src, unsigned short* __restrict__ dst, int R, int C)
{
  __shared__ float t[32][33];
  int tx = threadIdx.x & 31, ty = threadIdx.x >> 5;
  int c0 = blockIdx.x << 5, r0 = blockIdx.y << 5;
#pragma unroll
  for (int i = 0; i < 32; i += 8)
    t[ty + i][tx] = src[(size_t)(r0 + ty + i) * C + (c0 + tx)];
  __syncthreads();
#pragma unroll
  for (int i = 0; i < 32; i += 8)
    dst[(size_t)(c0 + ty + i) * R + (r0 + tx)] = f2bf(t[tx][ty + i]);
}

// ---------------- LayerNorm + clip + delta (fused) ----------------
__global__ __launch_bounds__(256) void ln_delta_kernel(
    const float* __restrict__ x, const float* __restrict__ lns,
    const float* __restrict__ lnb, const float* __restrict__ dtk,
    const float* __restrict__ dtb, unsigned short* __restrict__ xn,
    float* __restrict__ delta)
{
  const int row = blockIdx.x;
  const int tid = threadIdx.x;
  const float* xr = x + (size_t)row * H_DIM;
  float v[8];
  *(float4*)&v[0] = ((const float4*)xr)[tid * 2];
  *(float4*)&v[4] = ((const float4*)xr)[tid * 2 + 1];
  float s1 = 0.f, s2 = 0.f;
#pragma unroll
  for (int j = 0; j < 8; ++j) { s1 += v[j]; s2 += v[j] * v[j]; }
  __shared__ float red[8];
#pragma unroll
  for (int off = 32; off; off >>= 1) {
    s1 += __shfl_down(s1, off);
    s2 += __shfl_down(s2, off);
  }
  if ((tid & 63) == 0) { red[tid >> 6] = s1; red[4 + (tid >> 6)] = s2; }
  __syncthreads();
  float mean = (red[0] + red[1] + red[2] + red[3]) * (1.0f / H_DIM);
  float var  = (red[4] + red[5] + red[6] + red[7]) * (1.0f / H_DIM) - mean * mean;
  float rstd = rsqrtf(var + 1e-6f);

  float sc[8], bi[8], dk[8];
  *(float4*)&sc[0] = ((const float4*)lns)[tid * 2];
  *(float4*)&sc[4] = ((const float4*)lns)[tid * 2 + 1];
  *(float4*)&bi[0] = ((const float4*)lnb)[tid * 2];
  *(float4*)&bi[4] = ((const float4*)lnb)[tid * 2 + 1];
  *(float4*)&dk[0] = ((const float4*)dtk)[tid * 2];
  *(float4*)&dk[4] = ((const float4*)dtk)[tid * 2 + 1];

  float dot = 0.f;
  s16x8 o;
#pragma unroll
  for (int j = 0; j < 8; ++j) {
    float xv = (v[j] - mean) * rstd * sc[j] + bi[j];
    xv = fminf(fmaxf(xv, -1.0e6f), 1.0e6f);
    dot += xv * dk[j];
    o[j] = (short)f2bf(xv);
  }
  *(s16x8*)(xn + (size_t)row * H_DIM + tid * 8) = o;

  __syncthreads();  // everyone done reading red[]
#pragma unroll
  for (int off = 32; off; off >>= 1) dot += __shfl_down(dot, off);
  if ((tid & 63) == 0) red[tid >> 6] = dot;
  __syncthreads();
  if (tid == 0)
    delta[row] = __expf(red[0] + red[1] + red[2] + red[3] + dtb[0]);
}

// ---------------- sequential state recurrence ----------------
__global__ __launch_bounds__(256) void scan_kernel(
    const unsigned short* __restrict__ U, const float* __restrict__ delta,
    const float* __restrict__ Adiag, const float* __restrict__ ctx,
    unsigned short* __restrict__ states, float* __restrict__ finalSt)
{
  const int h = blockIdx.x * 256 + threadIdx.x;
  const int b = blockIdx.y;
  const float a = Adiag[h];
  float st = ctx[b * H_DIM + h];
  const unsigned short* u = U + (size_t)b * SEQ * H_DIM + h;
  unsigned short* so = states + (size_t)b * SEQ * H_DIM + h;
  const float* dl = delta + b * SEQ;
#pragma unroll 4
  for (int s = 0; s < SEQ; ++s) {
    float dec = __expf(dl[s] * a);
    float uv = bf2f(u[(size_t)s * H_DIM]);
    st = fmaf(st, dec, uv);
    so[(size_t)s * H_DIM] = f2bf(st);
  }
  finalSt[b * H_DIM + h] = st;
}

// ---------------- bf16 MFMA GEMM, 128x128 tile, BK=32 ----------------
// A: [M][K] bf16, Bt: [N][K] bf16 (pre-transposed). EPI: 0=f32 out, 1=bf16 out,
// 2=GLU: out = Y * sigmoid(acc + gbias)
template <int EPI>
__global__ __launch_bounds__(256) void gemm_bf16(
    const short* __restrict__ A, const short* __restrict__ Bt,
    float* __restrict__ outF, unsigned short* __restrict__ outH,
    const unsigned short* __restrict__ Ybf, const float* __restrict__ gbias,
    int M, int N, int K)
{
  __shared__ __align__(16) short As[128 * 32];
  __shared__ __align__(16) short Bs[128 * 32];
  const int tid = threadIdx.x;
  const int lane = tid & 63;
  const int wid = tid >> 6;
  const int wr = wid >> 1, wc = wid & 1;     // 2x2 wave grid, 64x64 each
  const int fr = lane & 15;                  // fragment row/col
  const int kb = (lane >> 4) << 3;           // k base within BK
  f32x4 acc[4][4] = {};

  const size_t aBase = ((size_t)blockIdx.x * 128) * K;
  const size_t bBase = ((size_t)blockIdx.y * 128) * K;

  for (int k0 = 0; k0 < K; k0 += 32) {
#pragma unroll
    for (int p = 0; p < 2; ++p) {
      const int li = (p << 8) + tid;          // 0..511
      const int r = li >> 2;                  // tile row
      const int c = (li & 3) << 3;            // tile col (bf16 elems)
      gl_lds16(A + aBase + (size_t)r * K + (k0 + c), &As[li << 3]);
      gl_lds16(Bt + bBase + (size_t)r * K + (k0 + c), &Bs[li << 3]);
    }
    asm volatile("s_waitcnt vmcnt(0)" ::: "memory");
    __syncthreads();

    s16x8 af[4], bfg[4];
#pragma unroll
    for (int m = 0; m < 4; ++m)
      af[m] = *(const s16x8*)&As[((wr << 6) + (m << 4) + fr) * 32 + kb];
#pragma unroll
    for (int n = 0; n < 4; ++n)
      bfg[n] = *(const s16x8*)&Bs[((wc << 6) + (n << 4) + fr) * 32 + kb];
#pragma unroll
    for (int m = 0; m < 4; ++m)
#pragma unroll
      for (int n = 0; n < 4; ++n)
        acc[m][n] = __builtin_amdgcn_mfma_f32_16x16x32_bf16(af[m], bfg[n], acc[m][n], 0, 0, 0);
    __syncthreads();
  }

  // epilogue: D layout col = lane&15, row = (lane>>4)*4 + i
  const int cr = (lane >> 4) << 2;
  const int cc = lane & 15;
  const size_t r0 = (size_t)blockIdx.x * 128 + (wr << 6);
  const size_t c0 = (size_t)blockIdx.y * 128 + (wc << 6);
#pragma unroll
  for (int m = 0; m < 4; ++m) {
#pragma unroll
    for (int n = 0; n < 4; ++n) {
#pragma unroll
      for (int i = 0; i < 4; ++i) {
        const size_t r = r0 + (m << 4) + cr + i;
        const size_t c = c0 + (n << 4) + cc;
        const float v = acc[m][n][i];
        if constexpr (EPI == 0) {
          outF[r * N + c] = v;
        } else if constexpr (EPI == 1) {
          outH[r * N + c] = f2bf(v);
        } else {
          const float g = v + gbias[c];
          const float y = bf2f(Ybf[r * N + c]);
          outF[r * N + c] = y * (1.0f / (1.0f + __expf(-g)));
        }
      }
    }
  }
}

extern "C" void kernel_launch(void* const* d_in, const int* in_sizes, int n_in,
                              void* d_out, int out_size, void* d_ws, size_t ws_size,
                              hipStream_t stream) {
  (void)in_sizes; (void)n_in; (void)out_size; (void)ws_size;
  const float* x     = (const float*)d_in[0];
  const float* ctx   = (const float*)d_in[1];
  const float* Adiag = (const float*)d_in[2];
  const float* Bm    = (const float*)d_in[3];
  const float* Cm    = (const float*)d_in[4];
  const float* dtk   = (const float*)d_in[5];
  const float* dtb   = (const float*)d_in[6];
  const float* gk    = (const float*)d_in[7];
  const float* gb    = (const float*)d_in[8];
  const float* lns   = (const float*)d_in[9];
  const float* lnb   = (const float*)d_in[10];
  float* outF = (float*)d_out;

  char* ws = (char*)d_ws;
  unsigned short* xnY    = (unsigned short*)ws; ws += (size_t)M_DIM * H_DIM * 2;  // xn, later Y
  unsigned short* U      = (unsigned short*)ws; ws += (size_t)M_DIM * H_DIM * 2;
  unsigned short* states = (unsigned short*)ws; ws += (size_t)M_DIM * H_DIM * 2;
  unsigned short* T1     = (unsigned short*)ws; ws += (size_t)H_DIM * H_DIM * 2;
  unsigned short* T2     = (unsigned short*)ws; ws += (size_t)H_DIM * H_DIM * 2;
  unsigned short* T3     = (unsigned short*)ws; ws += (size_t)H_DIM * H_DIM * 2;
  float* delta           = (float*)ws;          ws += (size_t)M_DIM * 4;

  dim3 tb(256);
  transpose_kernel<<<dim3(64, 64), tb, 0, stream>>>(Bm, T1, H_DIM, H_DIM);
  transpose_kernel<<<dim3(64, 64), tb, 0, stream>>>(Cm, T2, H_DIM, H_DIM);
  transpose_kernel<<<dim3(64, 64), tb, 0, stream>>>(gk, T3, H_DIM, H_DIM);
  ln_delta_kernel<<<M_DIM, tb, 0, stream>>>(x, lns, lnb, dtk, dtb, xnY, delta);
  gemm_bf16<1><<<dim3(64, 16), tb, 0, stream>>>(
      (const short*)xnY, (const short*)T1, nullptr, U, nullptr, nullptr,
      M_DIM, H_DIM, H_DIM);
  scan_kernel<<<dim3(H_DIM / 256, B_SZ), tb, 0, stream>>>(
      U, delta, Adiag, ctx, states, outF + (size_t)M_DIM * H_DIM);
  gemm_bf16<1><<<dim3(64, 16), tb, 0, stream>>>(
      (const short*)states, (const short*)T2, nullptr, xnY, nullptr, nullptr,
      M_DIM, H_DIM, H_DIM);
  gemm_bf16<2><<<dim3(64, 16), tb, 0, stream>>>(
      (const short*)xnY, (const short*)T3, outF, nullptr, xnY, gb,
      M_DIM, H_DIM, H_DIM);
}

// Round 2
// 332.681 us; speedup vs baseline: 1.4221x; 1.4221x over previous
//
#include <hip/hip_runtime.h>
#include <hip/hip_bf16.h>

#define H_DIM 2048
#define B_SZ  8
#define SEQ   1024
#define M_DIM (B_SZ*SEQ)   // 8192
#define KDIM  2048
#define NKT   (KDIM/64)    // 32 K-tiles

using f32x4 = __attribute__((ext_vector_type(4))) float;
using s16x8 = __attribute__((ext_vector_type(8))) short;

__device__ __forceinline__ float bf2f(unsigned short u) {
  unsigned int x = ((unsigned int)u) << 16;
  return __builtin_bit_cast(float, x);
}
__device__ __forceinline__ unsigned short f2bf(float f) {
  unsigned int x = __builtin_bit_cast(unsigned int, f);
  unsigned int r = (x + 0x7fffu + ((x >> 16) & 1u)) >> 16;
  return (unsigned short)r;
}

__device__ __forceinline__ void gl_lds16(const void* g, void* l) {
  __builtin_amdgcn_global_load_lds(
      (__attribute__((address_space(1))) void*)g,
      (__attribute__((address_space(3))) void*)l, 16, 0, 0);
}

// ---------------- transpose fp32 [R][C] -> bf16 [C][R] ----------------
__global__ __launch_bounds__(256) void transpose_kernel(
    const float* __restrict__ src, unsigned short* __restrict__ dst, int R, int C)
{
  __shared__ float t[32][33];
  int tx = threadIdx.x & 31, ty = threadIdx.x >> 5;
  int c0 = blockIdx.x << 5, r0 = blockIdx.y << 5;
#pragma unroll
  for (int i = 0; i < 32; i += 8)
    t[ty + i][tx] = src[(size_t)(r0 + ty + i) * C + (c0 + tx)];
  __syncthreads();
#pragma unroll
  for (int i = 0; i < 32; i += 8)
    dst[(size_t)(c0 + ty + i) * R + (r0 + tx)] = f2bf(t[tx][ty + i]);
}

// ---------------- LayerNorm + clip + delta (fused) ----------------
__global__ __launch_bounds__(256) void ln_delta_kernel(
    const float* __restrict__ x, const float* __restrict__ lns,
    const float* __restrict__ lnb, const float* __restrict__ dtk,
    const float* __restrict__ dtb, unsigned short* __restrict__ xn,
    float* __restrict__ delta)
{
  const int row = blockIdx.x;
  const int tid = threadIdx.x;
  const float* xr = x + (size_t)row * H_DIM;
  float v[8];
  *(float4*)&v[0] = ((const float4*)xr)[tid * 2];
  *(float4*)&v[4] = ((const float4*)xr)[tid * 2 + 1];
  float s1 = 0.f, s2 = 0.f;
#pragma unroll
  for (int j = 0; j < 8; ++j) { s1 += v[j]; s2 += v[j] * v[j]; }
  __shared__ float red[8];
#pragma unroll
  for (int off = 32; off; off >>= 1) {
    s1 += __shfl_down(s1, off);
    s2 += __shfl_down(s2, off);
  }
  if ((tid & 63) == 0) { red[tid >> 6] = s1; red[4 + (tid >> 6)] = s2; }
  __syncthreads();
  float mean = (red[0] + red[1] + red[2] + red[3]) * (1.0f / H_DIM);
  float var  = (red[4] + red[5] + red[6] + red[7]) * (1.0f / H_DIM) - mean * mean;
  float rstd = rsqrtf(var + 1e-6f);

  float sc[8], bi[8], dk[8];
  *(float4*)&sc[0] = ((const float4*)lns)[tid * 2];
  *(float4*)&sc[4] = ((const float4*)lns)[tid * 2 + 1];
  *(float4*)&bi[0] = ((const float4*)lnb)[tid * 2];
  *(float4*)&bi[4] = ((const float4*)lnb)[tid * 2 + 1];
  *(float4*)&dk[0] = ((const float4*)dtk)[tid * 2];
  *(float4*)&dk[4] = ((const float4*)dtk)[tid * 2 + 1];

  float dot = 0.f;
  s16x8 o;
#pragma unroll
  for (int j = 0; j < 8; ++j) {
    float xv = (v[j] - mean) * rstd * sc[j] + bi[j];
    xv = fminf(fmaxf(xv, -1.0e6f), 1.0e6f);
    dot += xv * dk[j];
    o[j] = (short)f2bf(xv);
  }
  *(s16x8*)(xn + (size_t)row * H_DIM + tid * 8) = o;

  __syncthreads();
#pragma unroll
  for (int off = 32; off; off >>= 1) dot += __shfl_down(dot, off);
  if ((tid & 63) == 0) red[tid >> 6] = dot;
  __syncthreads();
  if (tid == 0)
    delta[row] = __expf(red[0] + red[1] + red[2] + red[3] + dtb[0]);
}

// ---------------- sequential state recurrence ----------------
__global__ __launch_bounds__(256) void scan_kernel(
    const unsigned short* __restrict__ U, const float* __restrict__ delta,
    const float* __restrict__ Adiag, const float* __restrict__ ctx,
    unsigned short* __restrict__ states, float* __restrict__ finalSt)
{
  const int h = blockIdx.x * 256 + threadIdx.x;
  const int b = blockIdx.y;
  const float a = Adiag[h];
  float st = ctx[b * H_DIM + h];
  const unsigned short* u = U + (size_t)b * SEQ * H_DIM + h;
  unsigned short* so = states + (size_t)b * SEQ * H_DIM + h;
  const float* dl = delta + b * SEQ;
#pragma unroll 4
  for (int s = 0; s < SEQ; ++s) {
    float dec = __expf(dl[s] * a);
    float uv = bf2f(u[(size_t)s * H_DIM]);
    st = fmaf(st, dec, uv);
    so[(size_t)s * H_DIM] = f2bf(st);
  }
  finalSt[b * H_DIM + h] = st;
}

// ===================== 256x256 8-phase bf16 GEMM =====================
// A: [M=8192][K=2048] bf16, Bt: [N=2048][K=2048] bf16 (pre-transposed).
// 512 threads (8 waves, 2Mx4N), BK=64, 2x double-buffered LDS (128 KiB),
// XOR-swizzled LDS granules (pre-swizzled global source, swizzled ds_read),
// counted vmcnt(6) at phases 4/8 only, setprio around MFMA clusters.
// EPI: 1 = bf16 out, 2 = GLU: out = Y * sigmoid(acc + gbias)  (f32 out)

#define BAR_() { __builtin_amdgcn_sched_barrier(0); __builtin_amdgcn_s_barrier(); __builtin_amdgcn_sched_barrier(0); }
#define VMC(N) asm volatile("s_waitcnt vmcnt(" #N ")" ::: "memory");

#define RD_A03(PA0, PA1) { _Pragma("unroll") for (int i_ = 0; i_ < 4; ++i_) { \
    a0[i_] = *(const s16x8*)((PA0) + i_ * 4096); \
    a1[i_] = *(const s16x8*)((PA1) + i_ * 4096); } }
#define RD_A47(PA0, PA1) { _Pragma("unroll") for (int i_ = 0; i_ < 4; ++i_) { \
    a0[i_] = *(const s16x8*)((PA0) + 16384 + i_ * 4096); \
    a1[i_] = *(const s16x8*)((PA1) + 16384 + i_ * 4096); } }
#define RD_B01(PB0, PB1) { _Pragma("unroll") for (int j_ = 0; j_ < 2; ++j_) { \
    bq0[j_] = *(const s16x8*)((PB0) + j_ * 8192); \
    bq1[j_] = *(const s16x8*)((PB1) + j_ * 8192); } }
#define RD_B23(PB0, PB1) { _Pragma("unroll") for (int j_ = 2; j_ < 4; ++j_) { \
    bq0[j_] = *(const s16x8*)((PB0) + j_ * 8192); \
    bq1[j_] = *(const s16x8*)((PB1) + j_ * 8192); } }

#define Q_MM(IB, JB) { __builtin_amdgcn_s_setprio(1); \
  _Pragma("unroll") for (int i_ = 0; i_ < 4; ++i_) \
  _Pragma("unroll") for (int j_ = 0; j_ < 2; ++j_) { \
    acc[(IB)+i_][(JB)+j_] = __builtin_amdgcn_mfma_f32_16x16x32_bf16(a0[i_], bq0[(JB)+j_], acc[(IB)+i_][(JB)+j_], 0, 0, 0); \
    acc[(IB)+i_][(JB)+j_] = __builtin_amdgcn_mfma_f32_16x16x32_bf16(a1[i_], bq1[(JB)+j_], acc[(IB)+i_][(JB)+j_], 0, 0, 0); } \
  __builtin_amdgcn_s_setprio(0); }

#define STAGE_A(BUF, HH, TT) { const char* s_ = srcA + (HH) * 524288 + (TT) * 128; \
  char* d_ = ldsA + (BUF) * 32768 + (HH) * 16384 + tid16; \
  gl_lds16(s_, d_); gl_lds16(s_ + 262144, d_ + 8192); }
#define STAGE_B(BUF, HH, TT) { const char* s_ = srcB + (HH) * 524288 + (TT) * 128; \
  char* d_ = ldsB + (BUF) * 32768 + (HH) * 16384 + tid16; \
  gl_lds16(s_, d_); gl_lds16(s_ + 262144, d_ + 8192); }

template <int EPI>
__global__ __launch_bounds__(512, 2) void gemm8p(
    const char* __restrict__ Ab, const char* __restrict__ Bb,
    float* __restrict__ outF, unsigned short* __restrict__ outH,
    const unsigned short* __restrict__ Ybf, const float* __restrict__ gbias)
{
  extern __shared__ char lds[];
  char* ldsA = lds;            // 2 bufs x 32KB
  char* ldsB = lds + 65536;    // 2 bufs x 32KB

  const int tid  = threadIdx.x;
  const int lane = tid & 63, wid = tid >> 6;
  const int wr = wid >> 2, wc = wid & 3;       // 2x4 wave grid
  const int fr = lane & 15, kq = lane >> 4;

  const int bid  = blockIdx.x;                 // 256 blocks, %8==0 -> bijective
  const int wgid = (bid & 7) * 32 + (bid >> 3);
  const int bm = wgid & 31, bn = wgid >> 5;    // each XCD owns one N-panel

  // ---- staging source (pre-swizzled global, linear LDS dest) ----
  const int grow = tid >> 3;                          // 0..63
  const int gswz = ((tid & 7) ^ (grow & 7)) << 4;     // XOR granule swizzle
  const char* srcA = Ab + ((size_t)(bm * 256 + grow)) * 4096 + gswz;
  const char* srcB = Bb + ((size_t)(bn * 256 + grow)) * 4096 + gswz;
  const int tid16 = tid << 4;

  // ---- swizzled ds_read base pointers (per kk-slice, per buffer) ----
  const int sw0 = ((kq ^ (fr & 7)) << 4);
  const int sw1 = (((4 | kq) ^ (fr & 7)) << 4);
  const char* pa0b0 = ldsA + wr * 2048 + fr * 128 + sw0;
  const char* pa1b0 = ldsA + wr * 2048 + fr * 128 + sw1;
  const char* pa0b1 = pa0b0 + 32768;
  const char* pa1b1 = pa1b0 + 32768;
  const char* pb0b0 = ldsB + wc * 2048 + fr * 128 + sw0;
  const char* pb1b0 = ldsB + wc * 2048 + fr * 128 + sw1;
  const char* pb0b1 = pb0b0 + 32768;
  const char* pb1b1 = pb1b0 + 32768;

  f32x4 acc[8][4] = {};
  s16x8 a0[4], a1[4], bq0[4], bq1[4];

  // ---- prologue: 7 half-tiles (T0 fully + T1's first 3), 3 stay in flight ----
  STAGE_A(0, 0, 0); STAGE_B(0, 0, 0); STAGE_B(0, 1, 0); STAGE_A(0, 1, 0);
  STAGE_A(1, 0, 1); STAGE_B(1, 0, 1); STAGE_B(1, 1, 1);
  VMC(6);
  BAR_();

  // ---- main loop: 15 iters x 2 K-tiles; epilogue handles tiles 30,31 ----
  for (int t = 0; t < NKT / 2 - 1; ++t) {
    const int T0 = 2 * t;
    // P1 (tile T0, buf0): A i0-3 + B j01 (12 ds_reads); stage Ah1(T0+1)
    RD_A03(pa0b0, pa1b0); RD_B01(pb0b0, pb1b0);
    STAGE_A(1, 1, T0 + 1);
    BAR_(); Q_MM(0, 0); BAR_();
    // P2: B j23; stage Ah0(T0+2)
    RD_B23(pb0b0, pb1b0);
    STAGE_A(0, 0, T0 + 2);
    BAR_(); Q_MM(0, 2); BAR_();
    // P3: A i4-7; stage Bh0(T0+2)
    RD_A47(pa0b0, pa1b0);
    STAGE_B(0, 0, T0 + 2);
    BAR_(); Q_MM(4, 0); BAR_();
    // P4: regs only; stage Bh1(T0+2); counted vmcnt
    STAGE_B(0, 1, T0 + 2);
    BAR_(); Q_MM(4, 2); VMC(6); BAR_();
    // P5 (tile T0+1, buf1): A i0-3 + B j01; stage Ah1(T0+2)
    RD_A03(pa0b1, pa1b1); RD_B01(pb0b1, pb1b1);
    STAGE_A(0, 1, T0 + 2);
    BAR_(); Q_MM(0, 0); BAR_();
    // P6: B j23; stage Ah0(T0+3)
    RD_B23(pb0b1, pb1b1);
    STAGE_A(1, 0, T0 + 3);
    BAR_(); Q_MM(0, 2); BAR_();
    // P7: A i4-7; stage Bh0(T0+3)
    RD_A47(pa0b1, pa1b1);
    STAGE_B(1, 0, T0 + 3);
    BAR_(); Q_MM(4, 0); BAR_();
    // P8: stage Bh1(T0+3); counted vmcnt
    STAGE_B(1, 1, T0 + 3);
    BAR_(); Q_MM(4, 2); VMC(6); BAR_();
  }

  // ---- epilogue: tiles 30 (buf0) and 31 (buf1) ----
  RD_A03(pa0b0, pa1b0); RD_B01(pb0b0, pb1b0);
  STAGE_A(1, 1, 31);
  BAR_(); Q_MM(0, 0); BAR_();
  RD_B23(pb0b0, pb1b0);
  BAR_(); Q_MM(0, 2); BAR_();
  RD_A47(pa0b0, pa1b0);
  BAR_(); Q_MM(4, 0); BAR_();
  BAR_(); Q_MM(4, 2); VMC(0); BAR_();
  RD_A03(pa0b1, pa1b1); RD_B01(pb0b1, pb1b1);
  BAR_(); Q_MM(0, 0); BAR_();
  RD_B23(pb0b1, pb1b1);
  BAR_(); Q_MM(0, 2); BAR_();
  RD_A47(pa0b1, pa1b1);
  BAR_(); Q_MM(4, 0); BAR_();
  Q_MM(4, 2);

  // ---- C write: row=(2i+wr)*16 + (lane>>4)*4 + r, col=(4j+wc)*16 + (lane&15)
  const int cr = (lane >> 4) << 2;
  const int cc = lane & 15;
#pragma unroll
  for (int i = 0; i < 8; ++i) {
#pragma unroll
    for (int j = 0; j < 4; ++j) {
#pragma unroll
      for (int r = 0; r < 4; ++r) {
        const size_t row = (size_t)bm * 256 + (2 * i + wr) * 16 + cr + r;
        const size_t col = (size_t)bn * 256 + (4 * j + wc) * 16 + cc;
        const float v = acc[i][j][r];
        if constexpr (EPI == 1) {
          outH[row * H_DIM + col] = f2bf(v);
        } else {
          const float g = v + gbias[col];
          const float y = bf2f(Ybf[row * H_DIM + col]);
          outF[row * H_DIM + col] = y * (1.0f / (1.0f + __expf(-g)));
        }
      }
    }
  }
}

extern "C" void kernel_launch(void* const* d_in, const int* in_sizes, int n_in,
                              void* d_out, int out_size, void* d_ws, size_t ws_size,
                              hipStream_t stream) {
  (void)in_sizes; (void)n_in; (void)out_size; (void)ws_size;
  const float* x     = (const float*)d_in[0];
  const float* ctx   = (const float*)d_in[1];
  const float* Adiag = (const float*)d_in[2];
  const float* Bm    = (const float*)d_in[3];
  const float* Cm    = (const float*)d_in[4];
  const float* dtk   = (const float*)d_in[5];
  const float* dtb   = (const float*)d_in[6];
  const float* gk    = (const float*)d_in[7];
  const float* gb    = (const float*)d_in[8];
  const float* lns   = (const float*)d_in[9];
  const float* lnb   = (const float*)d_in[10];
  float* outF = (float*)d_out;

  char* ws = (char*)d_ws;
  unsigned short* xnY    = (unsigned short*)ws; ws += (size_t)M_DIM * H_DIM * 2;  // xn, later Y
  unsigned short* U      = (unsigned short*)ws; ws += (size_t)M_DIM * H_DIM * 2;
  unsigned short* states = (unsigned short*)ws; ws += (size_t)M_DIM * H_DIM * 2;
  unsigned short* T1     = (unsigned short*)ws; ws += (size_t)H_DIM * H_DIM * 2;
  unsigned short* T2     = (unsigned short*)ws; ws += (size_t)H_DIM * H_DIM * 2;
  unsigned short* T3     = (unsigned short*)ws; ws += (size_t)H_DIM * H_DIM * 2;
  float* delta           = (float*)ws;          ws += (size_t)M_DIM * 4;

  hipFuncSetAttribute((const void*)&gemm8p<1>,
                      hipFuncAttributeMaxDynamicSharedMemorySize, 131072);
  hipFuncSetAttribute((const void*)&gemm8p<2>,
                      hipFuncAttributeMaxDynamicSharedMemorySize, 131072);

  dim3 tb(256);
  transpose_kernel<<<dim3(64, 64), tb, 0, stream>>>(Bm, T1, H_DIM, H_DIM);
  transpose_kernel<<<dim3(64, 64), tb, 0, stream>>>(Cm, T2, H_DIM, H_DIM);
  transpose_kernel<<<dim3(64, 64), tb, 0, stream>>>(gk, T3, H_DIM, H_DIM);
  ln_delta_kernel<<<M_DIM, tb, 0, stream>>>(x, lns, lnb, dtk, dtb, xnY, delta);
  gemm8p<1><<<256, 512, 131072, stream>>>(
      (const char*)xnY, (const char*)T1, nullptr, U, nullptr, nullptr);
  scan_kernel<<<dim3(H_DIM / 256, B_SZ), tb, 0, stream>>>(
      U, delta, Adiag, ctx, states, outF + (size_t)M_DIM * H_DIM);
  gemm8p<1><<<256, 512, 131072, stream>>>(
      (const char*)states, (const char*)T2, nullptr, xnY, nullptr, nullptr);
  gemm8p<2><<<256, 512, 131072, stream>>>(
      (const char*)xnY, (const char*)T3, outF, nullptr, xnY, gb);
}

// Round 3
// 257.890 us; speedup vs baseline: 1.8345x; 1.2900x over previous
//
#include <hip/hip_runtime.h>
#include <hip/hip_bf16.h>

#define H_DIM 2048
#define B_SZ  8
#define SEQ   1024
#define M_DIM (B_SZ*SEQ)   // 8192
#define KDIM  2048
#define NKT   (KDIM/64)    // 32 K-tiles
#define CCH   32           // scan chunks
#define CLEN  (SEQ/CCH)    // 32 steps per chunk

using f32x4 = __attribute__((ext_vector_type(4))) float;
using s16x8 = __attribute__((ext_vector_type(8))) short;

__device__ __forceinline__ float bf2f(unsigned short u) {
  unsigned int x = ((unsigned int)u) << 16;
  return __builtin_bit_cast(float, x);
}
__device__ __forceinline__ unsigned short f2bf(float f) {
  unsigned int x = __builtin_bit_cast(unsigned int, f);
  unsigned int r = (x + 0x7fffu + ((x >> 16) & 1u)) >> 16;
  return (unsigned short)r;
}

__device__ __forceinline__ void gl_lds16(const void* g, void* l) {
  __builtin_amdgcn_global_load_lds(
      (__attribute__((address_space(1))) void*)g,
      (__attribute__((address_space(3))) void*)l, 16, 0, 0);
}

// ---------------- transpose fp32 [R][C] -> bf16 [C][R] ----------------
__global__ __launch_bounds__(256) void transpose_kernel(
    const float* __restrict__ src, unsigned short* __restrict__ dst, int R, int C)
{
  __shared__ float t[32][33];
  int tx = threadIdx.x & 31, ty = threadIdx.x >> 5;
  int c0 = blockIdx.x << 5, r0 = blockIdx.y << 5;
#pragma unroll
  for (int i = 0; i < 32; i += 8)
    t[ty + i][tx] = src[(size_t)(r0 + ty + i) * C + (c0 + tx)];
  __syncthreads();
#pragma unroll
  for (int i = 0; i < 32; i += 8)
    dst[(size_t)(c0 + ty + i) * R + (r0 + tx)] = f2bf(t[tx][ty + i]);
}

// ---------------- LayerNorm + clip + delta (fused) ----------------
__global__ __launch_bounds__(256) void ln_delta_kernel(
    const float* __restrict__ x, const float* __restrict__ lns,
    const float* __restrict__ lnb, const float* __restrict__ dtk,
    const float* __restrict__ dtb, unsigned short* __restrict__ xn,
    float* __restrict__ delta)
{
  const int row = blockIdx.x;
  const int tid = threadIdx.x;
  const float* xr = x + (size_t)row * H_DIM;
  float v[8];
  *(float4*)&v[0] = ((const float4*)xr)[tid * 2];
  *(float4*)&v[4] = ((const float4*)xr)[tid * 2 + 1];
  float s1 = 0.f, s2 = 0.f;
#pragma unroll
  for (int j = 0; j < 8; ++j) { s1 += v[j]; s2 += v[j] * v[j]; }
  __shared__ float red[8];
#pragma unroll
  for (int off = 32; off; off >>= 1) {
    s1 += __shfl_down(s1, off);
    s2 += __shfl_down(s2, off);
  }
  if ((tid & 63) == 0) { red[tid >> 6] = s1; red[4 + (tid >> 6)] = s2; }
  __syncthreads();
  float mean = (red[0] + red[1] + red[2] + red[3]) * (1.0f / H_DIM);
  float var  = (red[4] + red[5] + red[6] + red[7]) * (1.0f / H_DIM) - mean * mean;
  float rstd = rsqrtf(var + 1e-6f);

  float sc[8], bi[8], dk[8];
  *(float4*)&sc[0] = ((const float4*)lns)[tid * 2];
  *(float4*)&sc[4] = ((const float4*)lns)[tid * 2 + 1];
  *(float4*)&bi[0] = ((const float4*)lnb)[tid * 2];
  *(float4*)&bi[4] = ((const float4*)lnb)[tid * 2 + 1];
  *(float4*)&dk[0] = ((const float4*)dtk)[tid * 2];
  *(float4*)&dk[4] = ((const float4*)dtk)[tid * 2 + 1];

  float dot = 0.f;
  s16x8 o;
#pragma unroll
  for (int j = 0; j < 8; ++j) {
    float xv = (v[j] - mean) * rstd * sc[j] + bi[j];
    xv = fminf(fmaxf(xv, -1.0e6f), 1.0e6f);
    dot += xv * dk[j];
    o[j] = (short)f2bf(xv);
  }
  *(s16x8*)(xn + (size_t)row * H_DIM + tid * 8) = o;

  __syncthreads();
#pragma unroll
  for (int off = 32; off; off >>= 1) dot += __shfl_down(dot, off);
  if ((tid & 63) == 0) red[tid >> 6] = dot;
  __syncthreads();
  if (tid == 0)
    delta[row] = __expf(red[0] + red[1] + red[2] + red[3] + dtb[0]);
}

// ---------------- chunked parallel scan ----------------
// scan1: per (b, chunk, h4): local scan (zero init) -> Q, decay product -> P
__global__ __launch_bounds__(256) void scan1_kernel(
    const unsigned short* __restrict__ U, const float* __restrict__ delta,
    const float* __restrict__ Adiag, float* __restrict__ Q, float* __restrict__ P)
{
  const int h = blockIdx.x * 1024 + threadIdx.x * 4;
  const int c = blockIdx.y, b = blockIdx.z;
  const float4 a = *(const float4*)(Adiag + h);
  const unsigned short* u = U + ((size_t)b * SEQ + c * CLEN) * H_DIM + h;
  const float* dl = delta + b * SEQ + c * CLEN;
  float4 st = {0.f, 0.f, 0.f, 0.f};
  float4 pr = {1.f, 1.f, 1.f, 1.f};
#pragma unroll 8
  for (int s = 0; s < CLEN; ++s) {
    const float d = dl[s];
    const ushort4 uv = *(const ushort4*)(u + (size_t)s * H_DIM);
    const float dx = __expf(d * a.x), dy = __expf(d * a.y);
    const float dz = __expf(d * a.z), dw = __expf(d * a.w);
    st.x = fmaf(st.x, dx, bf2f(uv.x)); st.y = fmaf(st.y, dy, bf2f(uv.y));
    st.z = fmaf(st.z, dz, bf2f(uv.z)); st.w = fmaf(st.w, dw, bf2f(uv.w));
    pr.x *= dx; pr.y *= dy; pr.z *= dz; pr.w *= dw;
  }
  const size_t idx = ((size_t)b * CCH + c) * H_DIM + h;
  *(float4*)(Q + idx) = st;
  *(float4*)(P + idx) = pr;
}

// scan2: per (b,h): prefix over chunks -> sIn (incoming state per chunk), final
__global__ __launch_bounds__(256) void scan2_kernel(
    const float* __restrict__ Q, const float* __restrict__ P,
    const float* __restrict__ ctx, float* __restrict__ sIn,
    float* __restrict__ finalSt)
{
  const int h = blockIdx.x * 256 + threadIdx.x;
  const int b = blockIdx.y;
  float s = ctx[b * H_DIM + h];
#pragma unroll
  for (int c = 0; c < CCH; ++c) {
    const size_t idx = ((size_t)b * CCH + c) * H_DIM + h;
    sIn[idx] = s;
    s = fmaf(s, P[idx], Q[idx]);
  }
  finalSt[b * H_DIM + h] = s;
}

// scan3: replay chunk seeded with sIn, write bf16 states
__global__ __launch_bounds__(256) void scan3_kernel(
    const unsigned short* __restrict__ U, const float* __restrict__ delta,
    const float* __restrict__ Adiag, const float* __restrict__ sIn,
    unsigned short* __restrict__ states)
{
  const int h = blockIdx.x * 1024 + threadIdx.x * 4;
  const int c = blockIdx.y, b = blockIdx.z;
  const float4 a = *(const float4*)(Adiag + h);
  const unsigned short* u = U + ((size_t)b * SEQ + c * CLEN) * H_DIM + h;
  unsigned short* so = states + ((size_t)b * SEQ + c * CLEN) * H_DIM + h;
  const float* dl = delta + b * SEQ + c * CLEN;
  float4 st = *(const float4*)(sIn + ((size_t)b * CCH + c) * H_DIM + h);
#pragma unroll 8
  for (int s = 0; s < CLEN; ++s) {
    const float d = dl[s];
    const ushort4 uv = *(const ushort4*)(u + (size_t)s * H_DIM);
    const float dx = __expf(d * a.x), dy = __expf(d * a.y);
    const float dz = __expf(d * a.z), dw = __expf(d * a.w);
    st.x = fmaf(st.x, dx, bf2f(uv.x)); st.y = fmaf(st.y, dy, bf2f(uv.y));
    st.z = fmaf(st.z, dz, bf2f(uv.z)); st.w = fmaf(st.w, dw, bf2f(uv.w));
    ushort4 ov = { f2bf(st.x), f2bf(st.y), f2bf(st.z), f2bf(st.w) };
    *(ushort4*)(so + (size_t)s * H_DIM) = ov;
  }
}

// ===================== 256x256 8-phase bf16 GEMM =====================
// A: [M=8192][K=2048] bf16, Bt: [N=2048][K=2048] bf16 (pre-transposed).
// 512 threads (8 waves, 2Mx4N), BK=64, 2x double-buffered LDS (128 KiB),
// XOR-swizzled LDS granules (pre-swizzled global source, swizzled ds_read),
// counted vmcnt(6) at phases 4/8 only, setprio around MFMA clusters.
// EPI: 1 = bf16 out, 2 = GLU: out = Y * sigmoid(acc + gbias)  (f32 out)

#define BAR_() { __builtin_amdgcn_sched_barrier(0); __builtin_amdgcn_s_barrier(); __builtin_amdgcn_sched_barrier(0); }
#define VMC(N) asm volatile("s_waitcnt vmcnt(" #N ")" ::: "memory");

#define RD_A03(PA0, PA1) { _Pragma("unroll") for (int i_ = 0; i_ < 4; ++i_) { \
    a0[i_] = *(const s16x8*)((PA0) + i_ * 4096); \
    a1[i_] = *(const s16x8*)((PA1) + i_ * 4096); } }
#define RD_A47(PA0, PA1) { _Pragma("unroll") for (int i_ = 0; i_ < 4; ++i_) { \
    a0[i_] = *(const s16x8*)((PA0) + 16384 + i_ * 4096); \
    a1[i_] = *(const s16x8*)((PA1) + 16384 + i_ * 4096); } }
#define RD_B01(PB0, PB1) { _Pragma("unroll") for (int j_ = 0; j_ < 2; ++j_) { \
    bq0[j_] = *(const s16x8*)((PB0) + j_ * 8192); \
    bq1[j_] = *(const s16x8*)((PB1) + j_ * 8192); } }
#define RD_B23(PB0, PB1) { _Pragma("unroll") for (int j_ = 2; j_ < 4; ++j_) { \
    bq0[j_] = *(const s16x8*)((PB0) + j_ * 8192); \
    bq1[j_] = *(const s16x8*)((PB1) + j_ * 8192); } }

#define Q_MM(IB, JB) { __builtin_amdgcn_s_setprio(1); \
  _Pragma("unroll") for (int i_ = 0; i_ < 4; ++i_) \
  _Pragma("unroll") for (int j_ = 0; j_ < 2; ++j_) { \
    acc[(IB)+i_][(JB)+j_] = __builtin_amdgcn_mfma_f32_16x16x32_bf16(a0[i_], bq0[(JB)+j_], acc[(IB)+i_][(JB)+j_], 0, 0, 0); \
    acc[(IB)+i_][(JB)+j_] = __builtin_amdgcn_mfma_f32_16x16x32_bf16(a1[i_], bq1[(JB)+j_], acc[(IB)+i_][(JB)+j_], 0, 0, 0); } \
  __builtin_amdgcn_s_setprio(0); }

#define STAGE_A(BUF, HH, TT) { const char* s_ = srcA + (HH) * 524288 + (TT) * 128; \
  char* d_ = ldsA + (BUF) * 32768 + (HH) * 16384 + tid16; \
  gl_lds16(s_, d_); gl_lds16(s_ + 262144, d_ + 8192); }
#define STAGE_B(BUF, HH, TT) { const char* s_ = srcB + (HH) * 524288 + (TT) * 128; \
  char* d_ = ldsB + (BUF) * 32768 + (HH) * 16384 + tid16; \
  gl_lds16(s_, d_); gl_lds16(s_ + 8192, d_ + 8192); }

#undef STAGE_B
#define STAGE_B(BUF, HH, TT) { const char* s_ = srcB + (HH) * 524288 + (TT) * 128; \
  char* d_ = ldsB + (BUF) * 32768 + (HH) * 16384 + tid16; \
  gl_lds16(s_, d_); gl_lds16(s_ + 262144, d_ + 8192); }

template <int EPI>
__global__ __launch_bounds__(512, 2) void gemm8p(
    const char* __restrict__ Ab, const char* __restrict__ Bb,
    float* __restrict__ outF, unsigned short* __restrict__ outH,
    const unsigned short* __restrict__ Ybf, const float* __restrict__ gbias)
{
  extern __shared__ char lds[];
  char* ldsA = lds;            // 2 bufs x 32KB
  char* ldsB = lds + 65536;    // 2 bufs x 32KB

  const int tid  = threadIdx.x;
  const int lane = tid & 63, wid = tid >> 6;
  const int wr = wid >> 2, wc = wid & 3;       // 2x4 wave grid
  const int fr = lane & 15, kq = lane >> 4;

  const int bid  = blockIdx.x;                 // 256 blocks, %8==0 -> bijective
  const int wgid = (bid & 7) * 32 + (bid >> 3);
  const int bm = wgid & 31, bn = wgid >> 5;    // each XCD owns one N-panel

  // ---- staging source (pre-swizzled global, linear LDS dest) ----
  const int grow = tid >> 3;                          // 0..63
  const int gswz = ((tid & 7) ^ (grow & 7)) << 4;     // XOR granule swizzle
  const char* srcA = Ab + ((size_t)(bm * 256 + grow)) * 4096 + gswz;
  const char* srcB = Bb + ((size_t)(bn * 256 + grow)) * 4096 + gswz;
  const int tid16 = tid << 4;

  // ---- swizzled ds_read base pointers (per kk-slice, per buffer) ----
  const int sw0 = ((kq ^ (fr & 7)) << 4);
  const int sw1 = (((4 | kq) ^ (fr & 7)) << 4);
  const char* pa0b0 = ldsA + wr * 2048 + fr * 128 + sw0;
  const char* pa1b0 = ldsA + wr * 2048 + fr * 128 + sw1;
  const char* pa0b1 = pa0b0 + 32768;
  const char* pa1b1 = pa1b0 + 32768;
  const char* pb0b0 = ldsB + wc * 2048 + fr * 128 + sw0;
  const char* pb1b0 = ldsB + wc * 2048 + fr * 128 + sw1;
  const char* pb0b1 = pb0b0 + 32768;
  const char* pb1b1 = pb1b0 + 32768;

  f32x4 acc[8][4] = {};
  s16x8 a0[4], a1[4], bq0[4], bq1[4];

  // ---- prologue: 7 half-tiles (T0 fully + T1's first 3), 3 stay in flight ----
  STAGE_A(0, 0, 0); STAGE_B(0, 0, 0); STAGE_B(0, 1, 0); STAGE_A(0, 1, 0);
  STAGE_A(1, 0, 1); STAGE_B(1, 0, 1); STAGE_B(1, 1, 1);
  VMC(6);
  BAR_();

  // ---- main loop: 15 iters x 2 K-tiles; epilogue handles tiles 30,31 ----
  for (int t = 0; t < NKT / 2 - 1; ++t) {
    const int T0 = 2 * t;
    // P1 (tile T0, buf0): A i0-3 + B j01 (12 ds_reads); stage Ah1(T0+1)
    RD_A03(pa0b0, pa1b0); RD_B01(pb0b0, pb1b0);
    STAGE_A(1, 1, T0 + 1);
    BAR_(); Q_MM(0, 0); BAR_();
    // P2: B j23; stage Ah0(T0+2)
    RD_B23(pb0b0, pb1b0);
    STAGE_A(0, 0, T0 + 2);
    BAR_(); Q_MM(0, 2); BAR_();
    // P3: A i4-7; stage Bh0(T0+2)
    RD_A47(pa0b0, pa1b0);
    STAGE_B(0, 0, T0 + 2);
    BAR_(); Q_MM(4, 0); BAR_();
    // P4: regs only; stage Bh1(T0+2); counted vmcnt
    STAGE_B(0, 1, T0 + 2);
    BAR_(); Q_MM(4, 2); VMC(6); BAR_();
    // P5 (tile T0+1, buf1): A i0-3 + B j01; stage Ah1(T0+2)
    RD_A03(pa0b1, pa1b1); RD_B01(pb0b1, pb1b1);
    STAGE_A(0, 1, T0 + 2);
    BAR_(); Q_MM(0, 0); BAR_();
    // P6: B j23; stage Ah0(T0+3)
    RD_B23(pb0b1, pb1b1);
    STAGE_A(1, 0, T0 + 3);
    BAR_(); Q_MM(0, 2); BAR_();
    // P7: A i4-7; stage Bh0(T0+3)
    RD_A47(pa0b1, pa1b1);
    STAGE_B(1, 0, T0 + 3);
    BAR_(); Q_MM(4, 0); BAR_();
    // P8: stage Bh1(T0+3); counted vmcnt
    STAGE_B(1, 1, T0 + 3);
    BAR_(); Q_MM(4, 2); VMC(6); BAR_();
  }

  // ---- epilogue: tiles 30 (buf0) and 31 (buf1) ----
  RD_A03(pa0b0, pa1b0); RD_B01(pb0b0, pb1b0);
  STAGE_A(1, 1, 31);
  BAR_(); Q_MM(0, 0); BAR_();
  RD_B23(pb0b0, pb1b0);
  BAR_(); Q_MM(0, 2); BAR_();
  RD_A47(pa0b0, pa1b0);
  BAR_(); Q_MM(4, 0); BAR_();
  BAR_(); Q_MM(4, 2); VMC(0); BAR_();
  RD_A03(pa0b1, pa1b1); RD_B01(pb0b1, pb1b1);
  BAR_(); Q_MM(0, 0); BAR_();
  RD_B23(pb0b1, pb1b1);
  BAR_(); Q_MM(0, 2); BAR_();
  RD_A47(pa0b1, pa1b1);
  BAR_(); Q_MM(4, 0); BAR_();
  Q_MM(4, 2);

  // ---- C write: row=(2i+wr)*16 + (lane>>4)*4 + r, col=(4j+wc)*16 + (lane&15)
  const int cr = (lane >> 4) << 2;
  const int cc = lane & 15;
#pragma unroll
  for (int i = 0; i < 8; ++i) {
#pragma unroll
    for (int j = 0; j < 4; ++j) {
#pragma unroll
      for (int r = 0; r < 4; ++r) {
        const size_t row = (size_t)bm * 256 + (2 * i + wr) * 16 + cr + r;
        const size_t col = (size_t)bn * 256 + (4 * j + wc) * 16 + cc;
        const float v = acc[i][j][r];
        if constexpr (EPI == 1) {
          outH[row * H_DIM + col] = f2bf(v);
        } else {
          const float g = v + gbias[col];
          const float y = bf2f(Ybf[row * H_DIM + col]);
          outF[row * H_DIM + col] = y * (1.0f / (1.0f + __expf(-g)));
        }
      }
    }
  }
}

extern "C" void kernel_launch(void* const* d_in, const int* in_sizes, int n_in,
                              void* d_out, int out_size, void* d_ws, size_t ws_size,
                              hipStream_t stream) {
  (void)in_sizes; (void)n_in; (void)out_size; (void)ws_size;
  const float* x     = (const float*)d_in[0];
  const float* ctx   = (const float*)d_in[1];
  const float* Adiag = (const float*)d_in[2];
  const float* Bm    = (const float*)d_in[3];
  const float* Cm    = (const float*)d_in[4];
  const float* dtk   = (const float*)d_in[5];
  const float* dtb   = (const float*)d_in[6];
  const float* gk    = (const float*)d_in[7];
  const float* gb    = (const float*)d_in[8];
  const float* lns   = (const float*)d_in[9];
  const float* lnb   = (const float*)d_in[10];
  float* outF = (float*)d_out;

  char* ws = (char*)d_ws;
  unsigned short* xnY    = (unsigned short*)ws; ws += (size_t)M_DIM * H_DIM * 2;  // xn, later Y
  unsigned short* U      = (unsigned short*)ws; ws += (size_t)M_DIM * H_DIM * 2;
  unsigned short* states = (unsigned short*)ws; ws += (size_t)M_DIM * H_DIM * 2;
  unsigned short* T1     = (unsigned short*)ws; ws += (size_t)H_DIM * H_DIM * 2;
  unsigned short* T2     = (unsigned short*)ws; ws += (size_t)H_DIM * H_DIM * 2;
  unsigned short* T3     = (unsigned short*)ws; ws += (size_t)H_DIM * H_DIM * 2;
  float* delta           = (float*)ws;          ws += (size_t)M_DIM * 4;
  float* Qbuf            = (float*)ws;          ws += (size_t)B_SZ * CCH * H_DIM * 4;
  float* Pbuf            = (float*)ws;          ws += (size_t)B_SZ * CCH * H_DIM * 4;
  float* sInBuf          = (float*)ws;          ws += (size_t)B_SZ * CCH * H_DIM * 4;

  hipFuncSetAttribute((const void*)&gemm8p<1>,
                      hipFuncAttributeMaxDynamicSharedMemorySize, 131072);
  hipFuncSetAttribute((const void*)&gemm8p<2>,
                      hipFuncAttributeMaxDynamicSharedMemorySize, 131072);

  dim3 tb(256);
  transpose_kernel<<<dim3(64, 64), tb, 0, stream>>>(Bm, T1, H_DIM, H_DIM);
  transpose_kernel<<<dim3(64, 64), tb, 0, stream>>>(Cm, T2, H_DIM, H_DIM);
  transpose_kernel<<<dim3(64, 64), tb, 0, stream>>>(gk, T3, H_DIM, H_DIM);
  ln_delta_kernel<<<M_DIM, tb, 0, stream>>>(x, lns, lnb, dtk, dtb, xnY, delta);
  gemm8p<1><<<256, 512, 131072, stream>>>(
      (const char*)xnY, (const char*)T1, nullptr, U, nullptr, nullptr);
  scan1_kernel<<<dim3(H_DIM / 1024, CCH, B_SZ), tb, 0, stream>>>(
      U, delta, Adiag, Qbuf, Pbuf);
  scan2_kernel<<<dim3(H_DIM / 256, B_SZ), tb, 0, stream>>>(
      Qbuf, Pbuf, ctx, sInBuf, outF + (size_t)M_DIM * H_DIM);
  scan3_kernel<<<dim3(H_DIM / 1024, CCH, B_SZ), tb, 0, stream>>>(
      U, delta, Adiag, sInBuf, states);
  gemm8p<1><<<256, 512, 131072, stream>>>(
      (const char*)states, (const char*)T2, nullptr, xnY, nullptr, nullptr);
  gemm8p<2><<<256, 512, 131072, stream>>>(
      (const char*)xnY, (const char*)T3, outF, nullptr, xnY, gb);
}

// Round 4
// 256.621 us; speedup vs baseline: 1.8436x; 1.0049x over previous
//
#include <hip/hip_runtime.h>
#include <hip/hip_bf16.h>

#define H_DIM 2048
#define B_SZ  8
#define SEQ   1024
#define M_DIM (B_SZ*SEQ)   // 8192
#define KDIM  2048
#define NKT   (KDIM/64)    // 32 K-tiles
#define CCH   32           // scan chunks
#define CLEN  (SEQ/CCH)    // 32 steps per chunk

using f32x4 = __attribute__((ext_vector_type(4))) float;
using s16x8 = __attribute__((ext_vector_type(8))) short;

__device__ __forceinline__ float bf2f(unsigned short u) {
  unsigned int x = ((unsigned int)u) << 16;
  return __builtin_bit_cast(float, x);
}
__device__ __forceinline__ unsigned short f2bf(float f) {
  unsigned int x = __builtin_bit_cast(unsigned int, f);
  unsigned int r = (x + 0x7fffu + ((x >> 16) & 1u)) >> 16;
  return (unsigned short)r;
}

__device__ __forceinline__ void gl_lds16(const void* g, void* l) {
  __builtin_amdgcn_global_load_lds(
      (__attribute__((address_space(1))) void*)g,
      (__attribute__((address_space(3))) void*)l, 16, 0, 0);
}

// ---------------- transpose fp32 [R][C] -> bf16 [C][R] ----------------
__global__ __launch_bounds__(256) void transpose_kernel(
    const float* __restrict__ src, unsigned short* __restrict__ dst, int R, int C)
{
  __shared__ float t[32][33];
  int tx = threadIdx.x & 31, ty = threadIdx.x >> 5;
  int c0 = blockIdx.x << 5, r0 = blockIdx.y << 5;
#pragma unroll
  for (int i = 0; i < 32; i += 8)
    t[ty + i][tx] = src[(size_t)(r0 + ty + i) * C + (c0 + tx)];
  __syncthreads();
#pragma unroll
  for (int i = 0; i < 32; i += 8)
    dst[(size_t)(c0 + ty + i) * R + (r0 + tx)] = f2bf(t[tx][ty + i]);
}

// ---------------- LayerNorm + clip + delta (fused) ----------------
__global__ __launch_bounds__(256) void ln_delta_kernel(
    const float* __restrict__ x, const float* __restrict__ lns,
    const float* __restrict__ lnb, const float* __restrict__ dtk,
    const float* __restrict__ dtb, unsigned short* __restrict__ xn,
    float* __restrict__ delta)
{
  const int row = blockIdx.x;
  const int tid = threadIdx.x;
  const float* xr = x + (size_t)row * H_DIM;
  float v[8];
  *(float4*)&v[0] = ((const float4*)xr)[tid * 2];
  *(float4*)&v[4] = ((const float4*)xr)[tid * 2 + 1];
  float s1 = 0.f, s2 = 0.f;
#pragma unroll
  for (int j = 0; j < 8; ++j) { s1 += v[j]; s2 += v[j] * v[j]; }
  __shared__ float red[8];
#pragma unroll
  for (int off = 32; off; off >>= 1) {
    s1 += __shfl_down(s1, off);
    s2 += __shfl_down(s2, off);
  }
  if ((tid & 63) == 0) { red[tid >> 6] = s1; red[4 + (tid >> 6)] = s2; }
  __syncthreads();
  float mean = (red[0] + red[1] + red[2] + red[3]) * (1.0f / H_DIM);
  float var  = (red[4] + red[5] + red[6] + red[7]) * (1.0f / H_DIM) - mean * mean;
  float rstd = rsqrtf(var + 1e-6f);

  float sc[8], bi[8], dk[8];
  *(float4*)&sc[0] = ((const float4*)lns)[tid * 2];
  *(float4*)&sc[4] = ((const float4*)lns)[tid * 2 + 1];
  *(float4*)&bi[0] = ((const float4*)lnb)[tid * 2];
  *(float4*)&bi[4] = ((const float4*)lnb)[tid * 2 + 1];
  *(float4*)&dk[0] = ((const float4*)dtk)[tid * 2];
  *(float4*)&dk[4] = ((const float4*)dtk)[tid * 2 + 1];

  float dot = 0.f;
  s16x8 o;
#pragma unroll
  for (int j = 0; j < 8; ++j) {
    float xv = (v[j] - mean) * rstd * sc[j] + bi[j];
    xv = fminf(fmaxf(xv, -1.0e6f), 1.0e6f);
    dot += xv * dk[j];
    o[j] = (short)f2bf(xv);
  }
  *(s16x8*)(xn + (size_t)row * H_DIM + tid * 8) = o;

  __syncthreads();
#pragma unroll
  for (int off = 32; off; off >>= 1) dot += __shfl_down(dot, off);
  if ((tid & 63) == 0) red[tid >> 6] = dot;
  __syncthreads();
  if (tid == 0)
    delta[row] = __expf(red[0] + red[1] + red[2] + red[3] + dtb[0]);
}

// ---------------- chunked parallel scan ----------------
__global__ __launch_bounds__(256) void scan1_kernel(
    const unsigned short* __restrict__ U, const float* __restrict__ delta,
    const float* __restrict__ Adiag, float* __restrict__ Q, float* __restrict__ P)
{
  const int h = blockIdx.x * 1024 + threadIdx.x * 4;
  const int c = blockIdx.y, b = blockIdx.z;
  const float4 a = *(const float4*)(Adiag + h);
  const unsigned short* u = U + ((size_t)b * SEQ + c * CLEN) * H_DIM + h;
  const float* dl = delta + b * SEQ + c * CLEN;
  float4 st = {0.f, 0.f, 0.f, 0.f};
  float4 pr = {1.f, 1.f, 1.f, 1.f};
#pragma unroll 8
  for (int s = 0; s < CLEN; ++s) {
    const float d = dl[s];
    const ushort4 uv = *(const ushort4*)(u + (size_t)s * H_DIM);
    const float dx = __expf(d * a.x), dy = __expf(d * a.y);
    const float dz = __expf(d * a.z), dw = __expf(d * a.w);
    st.x = fmaf(st.x, dx, bf2f(uv.x)); st.y = fmaf(st.y, dy, bf2f(uv.y));
    st.z = fmaf(st.z, dz, bf2f(uv.z)); st.w = fmaf(st.w, dw, bf2f(uv.w));
    pr.x *= dx; pr.y *= dy; pr.z *= dz; pr.w *= dw;
  }
  const size_t idx = ((size_t)b * CCH + c) * H_DIM + h;
  *(float4*)(Q + idx) = st;
  *(float4*)(P + idx) = pr;
}

__global__ __launch_bounds__(256) void scan2_kernel(
    const float* __restrict__ Q, const float* __restrict__ P,
    const float* __restrict__ ctx, float* __restrict__ sIn,
    float* __restrict__ finalSt)
{
  const int h = blockIdx.x * 256 + threadIdx.x;
  const int b = blockIdx.y;
  float s = ctx[b * H_DIM + h];
#pragma unroll
  for (int c = 0; c < CCH; ++c) {
    const size_t idx = ((size_t)b * CCH + c) * H_DIM + h;
    sIn[idx] = s;
    s = fmaf(s, P[idx], Q[idx]);
  }
  finalSt[b * H_DIM + h] = s;
}

__global__ __launch_bounds__(256) void scan3_kernel(
    const unsigned short* __restrict__ U, const float* __restrict__ delta,
    const float* __restrict__ Adiag, const float* __restrict__ sIn,
    unsigned short* __restrict__ states)
{
  const int h = blockIdx.x * 1024 + threadIdx.x * 4;
  const int c = blockIdx.y, b = blockIdx.z;
  const float4 a = *(const float4*)(Adiag + h);
  const unsigned short* u = U + ((size_t)b * SEQ + c * CLEN) * H_DIM + h;
  unsigned short* so = states + ((size_t)b * SEQ + c * CLEN) * H_DIM + h;
  const float* dl = delta + b * SEQ + c * CLEN;
  float4 st = *(const float4*)(sIn + ((size_t)b * CCH + c) * H_DIM + h);
#pragma unroll 8
  for (int s = 0; s < CLEN; ++s) {
    const float d = dl[s];
    const ushort4 uv = *(const ushort4*)(u + (size_t)s * H_DIM);
    const float dx = __expf(d * a.x), dy = __expf(d * a.y);
    const float dz = __expf(d * a.z), dw = __expf(d * a.w);
    st.x = fmaf(st.x, dx, bf2f(uv.x)); st.y = fmaf(st.y, dy, bf2f(uv.y));
    st.z = fmaf(st.z, dz, bf2f(uv.z)); st.w = fmaf(st.w, dw, bf2f(uv.w));
    ushort4 ov = { f2bf(st.x), f2bf(st.y), f2bf(st.z), f2bf(st.w) };
    *(ushort4*)(so + (size_t)s * H_DIM) = ov;
  }
}

// ===================== 256x256 8-phase bf16 GEMM =====================
// XCD-grouped (8bm x 4bn per XCD), XOR-swizzled LDS, counted vmcnt(6),
// setprio MFMA clusters, LDS-staged coalesced epilogue.
// EPI: 1 = bf16 out, 2 = GLU: out = Y * sigmoid(acc + gbias)  (f32 out)

#define BAR_() { __builtin_amdgcn_sched_barrier(0); __builtin_amdgcn_s_barrier(); __builtin_amdgcn_sched_barrier(0); }
#define VMC(N) asm volatile("s_waitcnt vmcnt(" #N ")" ::: "memory");

#define RD_A03(PA0, PA1) { _Pragma("unroll") for (int i_ = 0; i_ < 4; ++i_) { \
    a0[i_] = *(const s16x8*)((PA0) + i_ * 4096); \
    a1[i_] = *(const s16x8*)((PA1) + i_ * 4096); } }
#define RD_A47(PA0, PA1) { _Pragma("unroll") for (int i_ = 0; i_ < 4; ++i_) { \
    a0[i_] = *(const s16x8*)((PA0) + 16384 + i_ * 4096); \
    a1[i_] = *(const s16x8*)((PA1) + 16384 + i_ * 4096); } }
#define RD_B01(PB0, PB1) { _Pragma("unroll") for (int j_ = 0; j_ < 2; ++j_) { \
    bq0[j_] = *(const s16x8*)((PB0) + j_ * 8192); \
    bq1[j_] = *(const s16x8*)((PB1) + j_ * 8192); } }
#define RD_B23(PB0, PB1) { _Pragma("unroll") for (int j_ = 2; j_ < 4; ++j_) { \
    bq0[j_] = *(const s16x8*)((PB0) + j_ * 8192); \
    bq1[j_] = *(const s16x8*)((PB1) + j_ * 8192); } }

#define Q_MM(IB, JB) { __builtin_amdgcn_s_setprio(1); \
  _Pragma("unroll") for (int i_ = 0; i_ < 4; ++i_) \
  _Pragma("unroll") for (int j_ = 0; j_ < 2; ++j_) { \
    acc[(IB)+i_][(JB)+j_] = __builtin_amdgcn_mfma_f32_16x16x32_bf16(a0[i_], bq0[(JB)+j_], acc[(IB)+i_][(JB)+j_], 0, 0, 0); \
    acc[(IB)+i_][(JB)+j_] = __builtin_amdgcn_mfma_f32_16x16x32_bf16(a1[i_], bq1[(JB)+j_], acc[(IB)+i_][(JB)+j_], 0, 0, 0); } \
  __builtin_amdgcn_s_setprio(0); }

#define STAGE_A(BUF, HH, TT) { const char* s_ = srcA + (HH) * 524288 + (TT) * 128; \
  char* d_ = ldsA + (BUF) * 32768 + (HH) * 16384 + tid16; \
  gl_lds16(s_, d_); gl_lds16(s_ + 262144, d_ + 8192); }
#define STAGE_B(BUF, HH, TT) { const char* s_ = srcB + (HH) * 524288 + (TT) * 128; \
  char* d_ = ldsB + (BUF) * 32768 + (HH) * 16384 + tid16; \
  gl_lds16(s_, d_); gl_lds16(s_ + 262144, d_ + 8192); }

template <int EPI>
__global__ __launch_bounds__(512, 2) void gemm8p(
    const char* __restrict__ Ab, const char* __restrict__ Bb,
    float* __restrict__ outF, unsigned short* __restrict__ outH,
    const unsigned short* __restrict__ Ybf, const float* __restrict__ gbias)
{
  extern __shared__ char lds[];
  char* ldsA = lds;            // 2 bufs x 32KB
  char* ldsB = lds + 65536;    // 2 bufs x 32KB

  const int tid  = threadIdx.x;
  const int lane = tid & 63, wid = tid >> 6;
  const int wr = wid >> 2, wc = wid & 3;       // 2x4 wave grid
  const int fr = lane & 15, kq = lane >> 4;

  // ---- XCD-grouped block swizzle: each XCD owns an 8(bm) x 4(bn) group ----
  const int bid = blockIdx.x;                  // 256 blocks, bid&7 -> XCD
  const int xcd = bid & 7;
  const int li  = bid >> 3;                    // 0..31 within XCD
  const int bm  = (xcd >> 1) * 8 + (li & 7);
  const int bn  = (xcd & 1) * 4 + (li >> 3);

  // ---- staging source (pre-swizzled global, linear LDS dest) ----
  const int grow = tid >> 3;                          // 0..63
  const int gswz = ((tid & 7) ^ (grow & 7)) << 4;     // XOR granule swizzle
  const char* srcA = Ab + ((size_t)(bm * 256 + grow)) * 4096 + gswz;
  const char* srcB = Bb + ((size_t)(bn * 256 + grow)) * 4096 + gswz;
  const int tid16 = tid << 4;

  // ---- swizzled ds_read base pointers ----
  const int sw0 = ((kq ^ (fr & 7)) << 4);
  const int sw1 = (((4 | kq) ^ (fr & 7)) << 4);
  const char* pa0b0 = ldsA + wr * 2048 + fr * 128 + sw0;
  const char* pa1b0 = ldsA + wr * 2048 + fr * 128 + sw1;
  const char* pa0b1 = pa0b0 + 32768;
  const char* pa1b1 = pa1b0 + 32768;
  const char* pb0b0 = ldsB + wc * 2048 + fr * 128 + sw0;
  const char* pb1b0 = ldsB + wc * 2048 + fr * 128 + sw1;
  const char* pb0b1 = pb0b0 + 32768;
  const char* pb1b1 = pb1b0 + 32768;

  f32x4 acc[8][4] = {};
  s16x8 a0[4], a1[4], bq0[4], bq1[4];

  // ---- prologue ----
  STAGE_A(0, 0, 0); STAGE_B(0, 0, 0); STAGE_B(0, 1, 0); STAGE_A(0, 1, 0);
  STAGE_A(1, 0, 1); STAGE_B(1, 0, 1); STAGE_B(1, 1, 1);
  VMC(6);
  BAR_();

  for (int t = 0; t < NKT / 2 - 1; ++t) {
    const int T0 = 2 * t;
    RD_A03(pa0b0, pa1b0); RD_B01(pb0b0, pb1b0);
    STAGE_A(1, 1, T0 + 1);
    BAR_(); Q_MM(0, 0); BAR_();
    RD_B23(pb0b0, pb1b0);
    STAGE_A(0, 0, T0 + 2);
    BAR_(); Q_MM(0, 2); BAR_();
    RD_A47(pa0b0, pa1b0);
    STAGE_B(0, 0, T0 + 2);
    BAR_(); Q_MM(4, 0); BAR_();
    STAGE_B(0, 1, T0 + 2);
    BAR_(); Q_MM(4, 2); VMC(6); BAR_();
    RD_A03(pa0b1, pa1b1); RD_B01(pb0b1, pb1b1);
    STAGE_A(0, 1, T0 + 2);
    BAR_(); Q_MM(0, 0); BAR_();
    RD_B23(pb0b1, pb1b1);
    STAGE_A(1, 0, T0 + 3);
    BAR_(); Q_MM(0, 2); BAR_();
    RD_A47(pa0b1, pa1b1);
    STAGE_B(1, 0, T0 + 3);
    BAR_(); Q_MM(4, 0); BAR_();
    STAGE_B(1, 1, T0 + 3);
    BAR_(); Q_MM(4, 2); VMC(6); BAR_();
  }

  // ---- epilogue K-tiles 30,31 ----
  RD_A03(pa0b0, pa1b0); RD_B01(pb0b0, pb1b0);
  STAGE_A(1, 1, 31);
  BAR_(); Q_MM(0, 0); BAR_();
  RD_B23(pb0b0, pb1b0);
  BAR_(); Q_MM(0, 2); BAR_();
  RD_A47(pa0b0, pa1b0);
  BAR_(); Q_MM(4, 0); BAR_();
  BAR_(); Q_MM(4, 2); VMC(0); BAR_();
  RD_A03(pa0b1, pa1b1); RD_B01(pb0b1, pb1b1);
  BAR_(); Q_MM(0, 0); BAR_();
  RD_B23(pb0b1, pb1b1);
  BAR_(); Q_MM(0, 2); BAR_();
  RD_A47(pa0b1, pa1b1);
  BAR_(); Q_MM(4, 0); BAR_();
  Q_MM(4, 2);

  // ---- LDS-staged coalesced C write ----
  // frag layout: row=(2i+wr)*16 + (lane>>4)*4 + r, col=(4j+wc)*16 + (lane&15)
  __syncthreads();  // all waves done with ds_reads; LDS is free
  const int cr = (lane >> 4) << 2;
  const int cc = lane & 15;
  if constexpr (EPI == 1) {
    // bf16 [256][256] tile, 512B rows, XOR-swizzled 16B granules
#pragma unroll
    for (int i = 0; i < 8; ++i)
#pragma unroll
      for (int j = 0; j < 4; ++j)
#pragma unroll
        for (int r = 0; r < 4; ++r) {
          const int row = (2 * i + wr) * 16 + cr + r;
          const int col = (4 * j + wc) * 16 + cc;
          const int off = (row * 512 + col * 2) ^ ((row & 7) << 4);
          *(unsigned short*)(lds + off) = f2bf(acc[i][j][r]);
        }
    __syncthreads();
#pragma unroll
    for (int it = 0; it < 16; ++it) {
      const int L = it * 8192 + tid * 16;
      const int row = L >> 9, inrow = L & 511;
      const s16x8 v = *(const s16x8*)(lds + (L ^ ((row & 7) << 4)));
      *(s16x8*)(outH + ((size_t)(bm * 256 + row)) * H_DIM + bn * 256 + (inrow >> 1)) = v;
    }
  } else {
    // GLU: two 128-row f32 passes, 1024B rows
#pragma unroll
    for (int p = 0; p < 2; ++p) {
      if (p) __syncthreads();
#pragma unroll
      for (int i = 4 * p; i < 4 * p + 4; ++i)
#pragma unroll
        for (int j = 0; j < 4; ++j)
#pragma unroll
          for (int r = 0; r < 4; ++r) {
            const int lrow = (2 * i + wr) * 16 + cr + r - 128 * p;
            const int col = (4 * j + wc) * 16 + cc;
            const int off = (lrow * 1024 + col * 4) ^ ((lrow & 7) << 4);
            *(float*)(lds + off) = acc[i][j][r];
          }
      __syncthreads();
#pragma unroll
      for (int it = 0; it < 16; ++it) {
        const int L = it * 8192 + tid * 16;
        const int lrow = L >> 10, inrow = L & 1023;
        const f32x4 v = *(const f32x4*)(lds + (L ^ ((lrow & 7) << 4)));
        const size_t growg = (size_t)(bm * 256 + 128 * p + lrow);
        const int gcol = bn * 256 + (inrow >> 2);
        const float4 gb4 = *(const float4*)(gbias + gcol);
        const ushort4 y4 = *(const ushort4*)(Ybf + growg * H_DIM + gcol);
        float4 o;
        o.x = bf2f(y4.x) / (1.f + __expf(-(v[0] + gb4.x)));
        o.y = bf2f(y4.y) / (1.f + __expf(-(v[1] + gb4.y)));
        o.z = bf2f(y4.z) / (1.f + __expf(-(v[2] + gb4.z)));
        o.w = bf2f(y4.w) / (1.f + __expf(-(v[3] + gb4.w)));
        *(float4*)(outF + growg * H_DIM + gcol) = o;
      }
    }
  }
}

extern "C" void kernel_launch(void* const* d_in, const int* in_sizes, int n_in,
                              void* d_out, int out_size, void* d_ws, size_t ws_size,
                              hipStream_t stream) {
  (void)in_sizes; (void)n_in; (void)out_size; (void)ws_size;
  const float* x     = (const float*)d_in[0];
  const float* ctx   = (const float*)d_in[1];
  const float* Adiag = (const float*)d_in[2];
  const float* Bm    = (const float*)d_in[3];
  const float* Cm    = (const float*)d_in[4];
  const float* dtk   = (const float*)d_in[5];
  const float* dtb   = (const float*)d_in[6];
  const float* gk    = (const float*)d_in[7];
  const float* gb    = (const float*)d_in[8];
  const float* lns   = (const float*)d_in[9];
  const float* lnb   = (const float*)d_in[10];
  float* outF = (float*)d_out;

  char* ws = (char*)d_ws;
  unsigned short* xnY    = (unsigned short*)ws; ws += (size_t)M_DIM * H_DIM * 2;  // xn, later Y
  unsigned short* U      = (unsigned short*)ws; ws += (size_t)M_DIM * H_DIM * 2;
  unsigned short* states = (unsigned short*)ws; ws += (size_t)M_DIM * H_DIM * 2;
  unsigned short* T1     = (unsigned short*)ws; ws += (size_t)H_DIM * H_DIM * 2;
  unsigned short* T2     = (unsigned short*)ws; ws += (size_t)H_DIM * H_DIM * 2;
  unsigned short* T3     = (unsigned short*)ws; ws += (size_t)H_DIM * H_DIM * 2;
  float* delta           = (float*)ws;          ws += (size_t)M_DIM * 4;
  float* Qbuf            = (float*)ws;          ws += (size_t)B_SZ * CCH * H_DIM * 4;
  float* Pbuf            = (float*)ws;          ws += (size_t)B_SZ * CCH * H_DIM * 4;
  float* sInBuf          = (float*)ws;          ws += (size_t)B_SZ * CCH * H_DIM * 4;

  hipFuncSetAttribute((const void*)&gemm8p<1>,
                      hipFuncAttributeMaxDynamicSharedMemorySize, 131072);
  hipFuncSetAttribute((const void*)&gemm8p<2>,
                      hipFuncAttributeMaxDynamicSharedMemorySize, 131072);

  dim3 tb(256);
  transpose_kernel<<<dim3(64, 64), tb, 0, stream>>>(Bm, T1, H_DIM, H_DIM);
  transpose_kernel<<<dim3(64, 64), tb, 0, stream>>>(Cm, T2, H_DIM, H_DIM);
  transpose_kernel<<<dim3(64, 64), tb, 0, stream>>>(gk, T3, H_DIM, H_DIM);
  ln_delta_kernel<<<M_DIM, tb, 0, stream>>>(x, lns, lnb, dtk, dtb, xnY, delta);
  gemm8p<1><<<256, 512, 131072, stream>>>(
      (const char*)xnY, (const char*)T1, nullptr, U, nullptr, nullptr);
  scan1_kernel<<<dim3(H_DIM / 1024, CCH, B_SZ), tb, 0, stream>>>(
      U, delta, Adiag, Qbuf, Pbuf);
  scan2_kernel<<<dim3(H_DIM / 256, B_SZ), tb, 0, stream>>>(
      Qbuf, Pbuf, ctx, sInBuf, outF + (size_t)M_DIM * H_DIM);
  scan3_kernel<<<dim3(H_DIM / 1024, CCH, B_SZ), tb, 0, stream>>>(
      U, delta, Adiag, sInBuf, states);
  gemm8p<1><<<256, 512, 131072, stream>>>(
      (const char*)states, (const char*)T2, nullptr, xnY, nullptr, nullptr);
  gemm8p<2><<<256, 512, 131072, stream>>>(
      (const char*)xnY, (const char*)T3, outF, nullptr, xnY, gb);
}